// Round 8
// baseline (151.717 us; speedup 1.0000x reference)
//
#include <hip/hip_runtime.h>
#include <hip/hip_bf16.h>
#include <hip/hip_cooperative_groups.h>
#include <cstdint>

// B=2048, C=256, P=15, channels=512, groups=4 (128 ch each)
// Primary: ONE cooperative kernel (512 blocks x 4 batches, 2 blocks/CU margin);
// z lives in LDS across the BN-stats grid barrier; x read once.
// Fallback (if cooperative launch errors): r7's proven 4-kernel pipeline.
#define EPS_ 1e-5f
#define NVALID_F 30720.0f

namespace cg = cooperative_groups;

typedef __bf16 bf16x8 __attribute__((ext_vector_type(8)));
typedef float f32x16 __attribute__((ext_vector_type(16)));
typedef float f32x4 __attribute__((ext_vector_type(4)));
typedef unsigned short u16x8 __attribute__((ext_vector_type(8)));

__device__ __forceinline__ unsigned short f2bf(float f) {
  unsigned u = __float_as_uint(f);
  u += 0x7FFFu + ((u >> 16) & 1u);   // RNE
  return (unsigned short)(u >> 16);
}
__device__ __forceinline__ float bf2f(unsigned short h) {
  return __uint_as_float((unsigned)h << 16);
}

// ---- prologue: conv_w f32 [4][128][128] -> bf16 MFMA B-fragments ----
// Wf[g][mt][ks][lane][j] = w[g][o=mt*32+(lane&31)][i=ks*16+(lane>>5)*8+j]
__global__ void k_wprep(const float* __restrict__ w, unsigned short* __restrict__ wf) {
  int q = blockIdx.x * 256 + threadIdx.x;  // 0..8191
  int l = q & 63, ks = (q >> 6) & 7, mt = (q >> 9) & 3, g = q >> 11;
  int o = mt * 32 + (l & 31);
  int i = ks * 16 + (l >> 5) * 8;
  const float* src = w + ((size_t)(g * 128 + o) * 128 + i);
  u16x8 v;
#pragma unroll
  for (int j = 0; j < 8; ++j) v[j] = f2bf(src[j]);
  *(u16x8*)(wf + (size_t)q * 8) = v;
}

// ================= PRIMARY: cooperative single kernel =================
// 512 blocks x 256 thr, 4 batches/block. LDS: Yt 64x520 u16 (66560) +
// aArr/bArr (4096) + red (256) = 70912 B -> 2 blocks/CU (margin vs r5's 4).
__global__ __launch_bounds__(256, 2) void k_coop2(const float* __restrict__ x,
                                                  const unsigned short* __restrict__ wf,
                                                  float2* __restrict__ Part,
                                                  const float* __restrict__ gamma,
                                                  const float* __restrict__ beta,
                                                  float2* __restrict__ AB,
                                                  float* __restrict__ out) {
  __shared__ __align__(16) unsigned short Yt[64 * 520];
  __shared__ float aArr[512], bArr[512];
  __shared__ float2 red[4][8];
  cg::grid_group grid = cg::this_grid();
  const int t = threadIdx.x;
  const int bid = blockIdx.x;
  const int b0 = bid * 4;

  // ---- phase A: stage 4 x-slabs through Yt union (coalesced), build Y ----
  {
    const f32x4* src = (const f32x4*)(x + (size_t)b0 * 3840);
    f32x4* dst = (f32x4*)Yt;
    for (int q = t; q < 3840; q += 256) dst[q] = src[q];   // 61440 B <= 66560 B
  }
  __syncthreads();
  float v[4][15];
  {
    const float* xsf = (const float*)Yt;
#pragma unroll
    for (int bi = 0; bi < 4; ++bi)
#pragma unroll
      for (int p = 0; p < 15; ++p) v[bi][p] = xsf[bi * 3840 + t * 15 + p];
  }
  __syncthreads();   // all reads done before Yt overwrite
#pragma unroll
  for (int bi = 0; bi < 4; ++bi) {
    float pm[5];
#pragma unroll
    for (int q = 0; q < 5; ++q)
      pm[q] = fmaxf(fmaxf(v[bi][3 * q], v[bi][3 * q + 1]), v[bi][3 * q + 2]);
    float mq[5];
    mq[0] = fmaxf(fmaxf(pm[1], pm[2]), fmaxf(pm[3], pm[4]));
    mq[1] = fmaxf(fmaxf(pm[0], pm[2]), fmaxf(pm[3], pm[4]));
    mq[2] = fmaxf(fmaxf(pm[0], pm[1]), fmaxf(pm[3], pm[4]));
    mq[3] = fmaxf(fmaxf(pm[0], pm[1]), fmaxf(pm[2], pm[4]));
    mq[4] = fmaxf(fmaxf(pm[0], pm[1]), fmaxf(pm[2], pm[3]));
    const int c0 = bi * 16;
#pragma unroll
    for (int p = 0; p < 15; ++p) {
      Yt[(c0 + p) * 520 + t] = f2bf(v[bi][p]);                      // xs
      Yt[(c0 + p) * 520 + 256 + t] = f2bf(mq[p / 3] - v[bi][p]);    // tmp
    }
    Yt[(c0 + 15) * 520 + t] = 0;        // pad rows: exact 0
    Yt[(c0 + 15) * 520 + 256 + t] = 0;
  }
  __syncthreads();

  // ---- phase B: MFMA over 2 n-tiles (rows 0-31, 32-63); z back into Yt ----
  {
    const int lane = t & 63, g = t >> 6;
    const int l31 = lane & 31, lh = lane >> 5;
    const bf16x8* Wfv = (const bf16x8*)wf;

    bf16x8 bfr0[8], bfr1[8];
    const unsigned short* yr0 = &Yt[l31 * 520 + g * 128 + lh * 8];
    const unsigned short* yr1 = &Yt[(32 + l31) * 520 + g * 128 + lh * 8];
#pragma unroll
    for (int ks = 0; ks < 8; ++ks) {
      bfr0[ks] = *(const bf16x8*)(yr0 + ks * 16);
      bfr1[ks] = *(const bf16x8*)(yr1 + ks * 16);
    }
    // wave g reads+writes only cols [g*128, g*128+128): no inter-wave hazard
    for (int mt = 0; mt < 4; ++mt) {
      bf16x8 wr[8];
#pragma unroll
      for (int ks = 0; ks < 8; ++ks)
        wr[ks] = Wfv[(size_t)((g * 4 + mt) * 8 + ks) * 64 + lane];
      f32x16 a0, a1;
#pragma unroll
      for (int r = 0; r < 16; ++r) { a0[r] = 0.f; a1[r] = 0.f; }
#pragma unroll
      for (int ks = 0; ks < 8; ++ks) {
        a0 = __builtin_amdgcn_mfma_f32_32x32x16_bf16(bfr0[ks], wr[ks], a0, 0, 0, 0);
        a1 = __builtin_amdgcn_mfma_f32_32x32x16_bf16(bfr1[ks], wr[ks], a1, 0, 0, 0);
      }
      float s = 0.f, s2 = 0.f;
#pragma unroll
      for (int r = 0; r < 16; ++r) {
        float v0 = a0[r], v1 = a1[r];
        s += v0 + v1; s2 = fmaf(v0, v0, fmaf(v1, v1, s2));
      }
      s += __shfl_xor(s, 32, 64);
      s2 += __shfl_xor(s2, 32, 64);
      const int ch = g * 128 + mt * 32 + l31;
      if (lane < 32) Part[(size_t)bid * 512 + ch] = make_float2(s, s2);
#pragma unroll
      for (int r = 0; r < 16; ++r) {
        int row = (r & 3) + 8 * (r >> 2) + 4 * lh;
        Yt[row * 520 + ch] = f2bf(a0[r]);          // pad rows written, never read
        Yt[(32 + row) * 520 + ch] = f2bf(a1[r]);
      }
    }
  }

  grid.sync();   // Part visible device-wide

  // ---- phase C: blocks 0..63 reduce 8 channels each (dense 64B lines) ----
  if (bid < 64) {
    const int chb = bid * 8;
    const int c = t & 7, r0 = t >> 3;   // 32 rows x 8 ch per pass
    float s = 0.f, s2 = 0.f;
    for (int k = 0; k < 16; ++k) {
      float2 vv = Part[(size_t)(r0 + 32 * k) * 512 + chb + c];
      s += vv.x; s2 += vv.y;
    }
    s += __shfl_xor(s, 8, 64);  s2 += __shfl_xor(s2, 8, 64);
    s += __shfl_xor(s, 16, 64); s2 += __shfl_xor(s2, 16, 64);
    s += __shfl_xor(s, 32, 64); s2 += __shfl_xor(s2, 32, 64);
    if ((t & 63) < 8) red[t >> 6][c] = make_float2(s, s2);
    __syncthreads();
    if (t < 8) {
      float S = 0.f, S2 = 0.f;
#pragma unroll
      for (int w = 0; w < 4; ++w) { S += red[w][t].x; S2 += red[w][t].y; }
      const float inv = 1.f / NVALID_F;
      float mean = S * inv;
      float var = fmaxf(S2 * inv - mean * mean, 0.f);
      float a = gamma[chb + t] * rsqrtf(var + EPS_);
      AB[chb + t] = make_float2(a, beta[chb + t] - mean * a);
    }
  }

  grid.sync();   // AB visible device-wide

  // ---- phase D: finalize from LDS z-tile ----
#pragma unroll
  for (int i = 0; i < 2; ++i) {
    int ch = i * 256 + t;
    float2 ab = AB[ch];
    aArr[ch] = ab.x; bArr[ch] = ab.y;
  }
  __syncthreads();
#pragma unroll
  for (int bi = 0; bi < 4; ++bi) {
    float2* slab = (float2*)(out + (size_t)(b0 + bi) * 7680);
#pragma unroll 5
    for (int k = 0; k < 15; ++k) {
      int e0 = k * 512 + 2 * t;
      int ch0 = e0 / 15, p0 = e0 - ch0 * 15;
      int e1 = e0 + 1;
      int ch1 = e1 / 15, p1 = e1 - ch1 * 15;
      float f0 = bf2f(Yt[(bi * 16 + p0) * 520 + ch0]);
      float f1 = bf2f(Yt[(bi * 16 + p1) * 520 + ch1]);
      slab[k * 256 + t] = make_float2(
          fmaxf(fmaf(f0, aArr[ch0], bArr[ch0]), 0.f),
          fmaxf(fmaf(f1, aArr[ch1], bArr[ch1]), 0.f));
    }
  }
}

// ================= FALLBACK: r7's proven 4-kernel pipeline =================
__device__ __forceinline__ void build_Y_union(const float* __restrict__ x, int b0, int t,
                                              unsigned short* __restrict__ Yt) {
  {
    const f32x4* src = (const f32x4*)(x + (size_t)b0 * 3840);
    f32x4* dst = (f32x4*)Yt;
    for (int q = t; q < 1920; q += 256) dst[q] = src[q];
  }
  __syncthreads();
  float v[2][15];
  const float* xsf = (const float*)Yt;
#pragma unroll
  for (int bi = 0; bi < 2; ++bi)
#pragma unroll
    for (int p = 0; p < 15; ++p) v[bi][p] = xsf[bi * 3840 + t * 15 + p];
  __syncthreads();
#pragma unroll
  for (int bi = 0; bi < 2; ++bi) {
    float pm[5];
#pragma unroll
    for (int q = 0; q < 5; ++q)
      pm[q] = fmaxf(fmaxf(v[bi][3 * q], v[bi][3 * q + 1]), v[bi][3 * q + 2]);
    float mq[5];
    mq[0] = fmaxf(fmaxf(pm[1], pm[2]), fmaxf(pm[3], pm[4]));
    mq[1] = fmaxf(fmaxf(pm[0], pm[2]), fmaxf(pm[3], pm[4]));
    mq[2] = fmaxf(fmaxf(pm[0], pm[1]), fmaxf(pm[3], pm[4]));
    mq[3] = fmaxf(fmaxf(pm[0], pm[1]), fmaxf(pm[2], pm[4]));
    mq[4] = fmaxf(fmaxf(pm[0], pm[1]), fmaxf(pm[2], pm[3]));
    const int c0 = bi * 16;
#pragma unroll
    for (int p = 0; p < 15; ++p) {
      Yt[(c0 + p) * 520 + t] = f2bf(v[bi][p]);
      Yt[(c0 + p) * 520 + 256 + t] = f2bf(mq[p / 3] - v[bi][p]);
    }
    Yt[(c0 + 15) * 520 + t] = 0;
    Yt[(c0 + 15) * 520 + 256 + t] = 0;
  }
}

__global__ __launch_bounds__(256, 4) void k_pass1(const float* __restrict__ x,
                                                  const unsigned short* __restrict__ wf,
                                                  float2* __restrict__ Part) {
  __shared__ __align__(16) unsigned short Yt[32 * 520];
  const int t = threadIdx.x;
  const int b0 = blockIdx.x * 2;
  build_Y_union(x, b0, t, Yt);
  __syncthreads();

  const int lane = t & 63, g = t >> 6;
  const int l31 = lane & 31, lh = lane >> 5;
  const bf16x8* Wfv = (const bf16x8*)wf;

  bf16x8 bfr[8];
  const unsigned short* yrow = &Yt[l31 * 520 + g * 128 + lh * 8];
#pragma unroll
  for (int ks = 0; ks < 8; ++ks)
    bfr[ks] = *(const bf16x8*)(yrow + ks * 16);

  for (int mt = 0; mt < 4; ++mt) {
    bf16x8 wr[8];
#pragma unroll
    for (int ks = 0; ks < 8; ++ks)
      wr[ks] = Wfv[(size_t)((g * 4 + mt) * 8 + ks) * 64 + lane];
    f32x16 acc;
#pragma unroll
    for (int r = 0; r < 16; ++r) acc[r] = 0.f;
#pragma unroll
    for (int ks = 0; ks < 8; ++ks)
      acc = __builtin_amdgcn_mfma_f32_32x32x16_bf16(bfr[ks], wr[ks], acc, 0, 0, 0);
    float s = 0.f, s2 = 0.f;
#pragma unroll
    for (int r = 0; r < 16; ++r) { float vv = acc[r]; s += vv; s2 = fmaf(vv, vv, s2); }
    s += __shfl_xor(s, 32, 64);
    s2 += __shfl_xor(s2, 32, 64);
    const int ch = g * 128 + mt * 32 + l31;
    if (lane < 32) Part[(size_t)blockIdx.x * 512 + ch] = make_float2(s, s2);
  }
}

__global__ void k_stats(const float2* __restrict__ Part,
                        const float* __restrict__ gamma, const float* __restrict__ beta,
                        float2* __restrict__ AB) {
  const int t = threadIdx.x;
  const int chb = blockIdx.x * 8;
  const int c = t & 7, r0 = t >> 3;
  float s = 0.f, s2 = 0.f;
  for (int k = 0; k < 32; ++k) {
    float2 vv = Part[(size_t)(r0 + 32 * k) * 512 + chb + c];
    s += vv.x; s2 += vv.y;
  }
  s += __shfl_xor(s, 8, 64);  s2 += __shfl_xor(s2, 8, 64);
  s += __shfl_xor(s, 16, 64); s2 += __shfl_xor(s2, 16, 64);
  s += __shfl_xor(s, 32, 64); s2 += __shfl_xor(s2, 32, 64);
  __shared__ float2 red[4][8];
  if ((t & 63) < 8) red[t >> 6][c] = make_float2(s, s2);
  __syncthreads();
  if (t < 8) {
    float S = 0.f, S2 = 0.f;
#pragma unroll
    for (int w = 0; w < 4; ++w) { S += red[w][t].x; S2 += red[w][t].y; }
    const float inv = 1.f / NVALID_F;
    float mean = S * inv;
    float var = fmaxf(S2 * inv - mean * mean, 0.f);
    float a = gamma[chb + t] * rsqrtf(var + EPS_);
    AB[chb + t] = make_float2(a, beta[chb + t] - mean * a);
  }
}

__global__ __launch_bounds__(256, 4) void k_pass2(const float* __restrict__ x,
                                                  const unsigned short* __restrict__ wf,
                                                  const float2* __restrict__ AB,
                                                  float* __restrict__ out) {
  __shared__ __align__(16) unsigned short Yt[32 * 520];
  __shared__ float aArr[512], bArr[512];
  const int t = threadIdx.x;
  const int b0 = blockIdx.x * 2;

#pragma unroll
  for (int i = 0; i < 2; ++i) {
    int ch = i * 256 + t;
    float2 ab = AB[ch];
    aArr[ch] = ab.x; bArr[ch] = ab.y;
  }
  build_Y_union(x, b0, t, Yt);
  __syncthreads();

  {
    const int lane = t & 63, g = t >> 6;
    const int l31 = lane & 31, lh = lane >> 5;
    const bf16x8* Wfv = (const bf16x8*)wf;

    bf16x8 bfr[8];
    const unsigned short* yrow = &Yt[l31 * 520 + g * 128 + lh * 8];
#pragma unroll
    for (int ks = 0; ks < 8; ++ks)
      bfr[ks] = *(const bf16x8*)(yrow + ks * 16);

    for (int mt = 0; mt < 4; ++mt) {
      bf16x8 wr[8];
#pragma unroll
      for (int ks = 0; ks < 8; ++ks)
        wr[ks] = Wfv[(size_t)((g * 4 + mt) * 8 + ks) * 64 + lane];
      f32x16 acc;
#pragma unroll
      for (int r = 0; r < 16; ++r) acc[r] = 0.f;
#pragma unroll
      for (int ks = 0; ks < 8; ++ks)
        acc = __builtin_amdgcn_mfma_f32_32x32x16_bf16(bfr[ks], wr[ks], acc, 0, 0, 0);
      const int ch = g * 128 + mt * 32 + l31;
#pragma unroll
      for (int r = 0; r < 16; ++r) {
        int row = (r & 3) + 8 * (r >> 2) + 4 * lh;
        Yt[row * 520 + ch] = f2bf(acc[r]);
      }
    }
  }
  __syncthreads();

#pragma unroll
  for (int bi = 0; bi < 2; ++bi) {
    float2* slab = (float2*)(out + (size_t)(b0 + bi) * 7680);
#pragma unroll 5
    for (int k = 0; k < 15; ++k) {
      int e0 = k * 512 + 2 * t;
      int ch0 = e0 / 15, p0 = e0 - ch0 * 15;
      int e1 = e0 + 1;
      int ch1 = e1 / 15, p1 = e1 - ch1 * 15;
      float f0 = bf2f(Yt[(bi * 16 + p0) * 520 + ch0]);
      float f1 = bf2f(Yt[(bi * 16 + p1) * 520 + ch1]);
      slab[k * 256 + t] = make_float2(
          fmaxf(fmaf(f0, aArr[ch0], bArr[ch0]), 0.f),
          fmaxf(fmaf(f1, aArr[ch1], bArr[ch1]), 0.f));
    }
  }
}

extern "C" void kernel_launch(void* const* d_in, const int* in_sizes, int n_in,
                              void* d_out, int out_size, void* d_ws, size_t ws_size,
                              hipStream_t stream) {
  const float* x = (const float*)d_in[0];
  const float* cw = (const float*)d_in[1];
  // d_in[2] = conv_b: cancelled exactly by training-mode BN -> unused
  const float* gamma = (const float*)d_in[3];
  const float* beta = (const float*)d_in[4];

  unsigned short* wf = (unsigned short*)d_ws;             // 128 KB
  float2* Part = (float2*)(wf + 65536);                   // up to 4 MB
  float2* AB = Part + (size_t)1024 * 512;                 // 4 KB
  float* outf = (float*)d_out;

  hipLaunchKernelGGL(k_wprep, dim3(32), dim3(256), 0, stream, cw, wf);

  void* args[] = {(void*)&x, (void*)&wf, (void*)&Part, (void*)&gamma,
                  (void*)&beta, (void*)&AB, (void*)&outf};
  hipError_t cerr = hipLaunchCooperativeKernel((const void*)k_coop2, dim3(512),
                                               dim3(256), args, 0, stream);
  if (cerr != hipSuccess) {
    // fallback: r7's proven pipeline (deterministic: same decision every call)
    hipLaunchKernelGGL(k_pass1, dim3(1024), dim3(256), 0, stream, x, wf, Part);
    hipLaunchKernelGGL(k_stats, dim3(64), dim3(256), 0, stream, Part, gamma, beta, AB);
    hipLaunchKernelGGL(k_pass2, dim3(1024), dim3(256), 0, stream, x, wf, AB, outf);
  }
}

// Round 9
// 65.080 us; speedup vs baseline: 2.3313x; 2.3313x over previous
//
#include <hip/hip_runtime.h>
#include <hip/hip_bf16.h>
#include <cstdint>

// B=2048, C=256, P=15, channels=512, groups=4 (128 ch each)
// r9: 3-kernel chain. pass1 converts W directly in registers (no wprep kernel)
// and blocks 0-31 emit the wf fragment buffer for pass2. stats/pass2 = r7.
#define EPS_ 1e-5f
#define NVALID_F 30720.0f

typedef __bf16 bf16x8 __attribute__((ext_vector_type(8)));
typedef float f32x16 __attribute__((ext_vector_type(16)));
typedef float f32x4 __attribute__((ext_vector_type(4)));
typedef unsigned short u16x8 __attribute__((ext_vector_type(8)));

__device__ __forceinline__ unsigned short f2bf(float f) {
  unsigned u = __float_as_uint(f);
  u += 0x7FFFu + ((u >> 16) & 1u);   // RNE
  return (unsigned short)(u >> 16);
}
__device__ __forceinline__ float bf2f(unsigned short h) {
  return __uint_as_float((unsigned)h << 16);
}

// pack 8 consecutive f32 -> bf16x8 via HW packed RNE converts
__device__ __forceinline__ bf16x8 cvt8(const float* __restrict__ s8) {
  f32x4 a = *(const f32x4*)(s8);
  f32x4 b = *(const f32x4*)(s8 + 4);
  union { __hip_bfloat162 h2[4]; bf16x8 v; } u;
  u.h2[0] = __float22bfloat162_rn({a[0], a[1]});
  u.h2[1] = __float22bfloat162_rn({a[2], a[3]});
  u.h2[2] = __float22bfloat162_rn({b[0], b[1]});
  u.h2[3] = __float22bfloat162_rn({b[2], b[3]});
  return u.v;
}

// Build phase shared by both passes: stage 2 x-slabs through Yt union
// (coalesced), then overwrite Yt with bf16 Y = [xs | tmp].
__device__ __forceinline__ void build_Y_union(const float* __restrict__ x, int b0, int t,
                                              unsigned short* __restrict__ Yt) {
  {
    const f32x4* src = (const f32x4*)(x + (size_t)b0 * 3840);
    f32x4* dst = (f32x4*)Yt;
    for (int q = t; q < 1920; q += 256) dst[q] = src[q];
  }
  __syncthreads();
  float v[2][15];
  const float* xsf = (const float*)Yt;
#pragma unroll
  for (int bi = 0; bi < 2; ++bi)
#pragma unroll
    for (int p = 0; p < 15; ++p) v[bi][p] = xsf[bi * 3840 + t * 15 + p];
  __syncthreads();   // all reads done before Yt overwrite
#pragma unroll
  for (int bi = 0; bi < 2; ++bi) {
    float pm[5];
#pragma unroll
    for (int q = 0; q < 5; ++q)
      pm[q] = fmaxf(fmaxf(v[bi][3 * q], v[bi][3 * q + 1]), v[bi][3 * q + 2]);
    float mq[5];
    mq[0] = fmaxf(fmaxf(pm[1], pm[2]), fmaxf(pm[3], pm[4]));
    mq[1] = fmaxf(fmaxf(pm[0], pm[2]), fmaxf(pm[3], pm[4]));
    mq[2] = fmaxf(fmaxf(pm[0], pm[1]), fmaxf(pm[3], pm[4]));
    mq[3] = fmaxf(fmaxf(pm[0], pm[1]), fmaxf(pm[2], pm[4]));
    mq[4] = fmaxf(fmaxf(pm[0], pm[1]), fmaxf(pm[2], pm[3]));
    const int c0 = bi * 16;
#pragma unroll
    for (int p = 0; p < 15; ++p) {
      Yt[(c0 + p) * 520 + t] = f2bf(v[bi][p]);                      // xs -> ch 0..255
      Yt[(c0 + p) * 520 + 256 + t] = f2bf(mq[p / 3] - v[bi][p]);    // tmp -> ch 256..511
    }
    Yt[(c0 + 15) * 520 + t] = 0;        // pad rows: exact 0 (z=0 -> stats unaffected)
    Yt[(c0 + 15) * 520 + 256 + t] = 0;
  }
}

// ---- pass 1: GEMM with direct W conversion; per-block (s,s2) partials.
//      Blocks 0-31 also write the wf fragment buffer for pass2. ----
__global__ __launch_bounds__(256, 4) void k_pass1(const float* __restrict__ x,
                                                  const float* __restrict__ w,
                                                  unsigned short* __restrict__ wf,
                                                  float2* __restrict__ Part) {
  __shared__ __align__(16) unsigned short Yt[32 * 520];
  const int t = threadIdx.x;
  const int b0 = blockIdx.x * 2;

  // blocks 0..31: emit wf (old k_wprep body) — independent of this block's GEMM
  if (blockIdx.x < 32) {
    int q = blockIdx.x * 256 + t;     // 0..8191
    int l = q & 63, ks = (q >> 6) & 7, mt = (q >> 9) & 3, g = q >> 11;
    int o = mt * 32 + (l & 31);
    int i = ks * 16 + (l >> 5) * 8;
    const float* src = w + ((size_t)(g * 128 + o) * 128 + i);
    u16x8 vv;
#pragma unroll
    for (int j = 0; j < 8; ++j) vv[j] = f2bf(src[j]);
    *(u16x8*)(wf + (size_t)q * 8) = vv;
  }

  build_Y_union(x, b0, t, Yt);
  __syncthreads();

  const int lane = t & 63, g = t >> 6;
  const int l31 = lane & 31, lh = lane >> 5;

  bf16x8 bfr[8];
  const unsigned short* yrow = &Yt[l31 * 520 + g * 128 + lh * 8];
#pragma unroll
  for (int ks = 0; ks < 8; ++ks)
    bfr[ks] = *(const bf16x8*)(yrow + ks * 16);

  // W rows for this lane: w[g][mt*32+l31][ks*16+lh*8 .. +8]  (32B-aligned)
  const float* wbase = w + ((size_t)(g * 128 + l31) * 128 + lh * 8);
  for (int mt = 0; mt < 4; ++mt) {
    const float* wrow = wbase + (size_t)mt * 32 * 128;
    bf16x8 wr[8];
#pragma unroll
    for (int ks = 0; ks < 8; ++ks) wr[ks] = cvt8(wrow + ks * 16);
    f32x16 acc;
#pragma unroll
    for (int r = 0; r < 16; ++r) acc[r] = 0.f;
#pragma unroll
    for (int ks = 0; ks < 8; ++ks)
      acc = __builtin_amdgcn_mfma_f32_32x32x16_bf16(bfr[ks], wr[ks], acc, 0, 0, 0);
    float s = 0.f, s2 = 0.f;
#pragma unroll
    for (int r = 0; r < 16; ++r) { float vv = acc[r]; s += vv; s2 = fmaf(vv, vv, s2); }
    s += __shfl_xor(s, 32, 64);
    s2 += __shfl_xor(s2, 32, 64);
    const int ch = g * 128 + mt * 32 + l31;
    if (lane < 32) Part[(size_t)blockIdx.x * 512 + ch] = make_float2(s, s2);
  }
}

// ---- stats: 64 blocks x 8 ch; dense 64B-line reads of Part ----
__global__ void k_stats(const float2* __restrict__ Part,
                        const float* __restrict__ gamma, const float* __restrict__ beta,
                        float2* __restrict__ AB) {
  const int t = threadIdx.x;
  const int chb = blockIdx.x * 8;
  const int c = t & 7, r0 = t >> 3;
  float s = 0.f, s2 = 0.f;
  for (int k = 0; k < 32; ++k) {
    float2 vv = Part[(size_t)(r0 + 32 * k) * 512 + chb + c];
    s += vv.x; s2 += vv.y;
  }
  s += __shfl_xor(s, 8, 64);  s2 += __shfl_xor(s2, 8, 64);
  s += __shfl_xor(s, 16, 64); s2 += __shfl_xor(s2, 16, 64);
  s += __shfl_xor(s, 32, 64); s2 += __shfl_xor(s2, 32, 64);
  __shared__ float2 red[4][8];
  if ((t & 63) < 8) red[t >> 6][c] = make_float2(s, s2);
  __syncthreads();
  if (t < 8) {
    float S = 0.f, S2 = 0.f;
#pragma unroll
    for (int w = 0; w < 4; ++w) { S += red[w][t].x; S2 += red[w][t].y; }
    const float inv = 1.f / NVALID_F;
    float mean = S * inv;
    float var = fmaxf(S2 * inv - mean * mean, 0.f);
    float a = gamma[chb + t] * rsqrtf(var + EPS_);
    AB[chb + t] = make_float2(a, beta[chb + t] - mean * a);
  }
}

// ---- pass 2: recompute GEMM (x L3-hot, wf fragments), z-tile in LDS, finalize ----
__global__ __launch_bounds__(256, 4) void k_pass2(const float* __restrict__ x,
                                                  const unsigned short* __restrict__ wf,
                                                  const float2* __restrict__ AB,
                                                  float* __restrict__ out) {
  __shared__ __align__(16) unsigned short Yt[32 * 520];
  __shared__ float aArr[512], bArr[512];
  const int t = threadIdx.x;
  const int b0 = blockIdx.x * 2;

#pragma unroll
  for (int i = 0; i < 2; ++i) {
    int ch = i * 256 + t;
    float2 ab = AB[ch];
    aArr[ch] = ab.x; bArr[ch] = ab.y;
  }
  build_Y_union(x, b0, t, Yt);
  __syncthreads();

  {
    const int lane = t & 63, g = t >> 6;
    const int l31 = lane & 31, lh = lane >> 5;
    const bf16x8* Wfv = (const bf16x8*)wf;

    bf16x8 bfr[8];
    const unsigned short* yrow = &Yt[l31 * 520 + g * 128 + lh * 8];
#pragma unroll
    for (int ks = 0; ks < 8; ++ks)
      bfr[ks] = *(const bf16x8*)(yrow + ks * 16);

    // wave g reads+writes only cols [g*128, g*128+128): no inter-wave hazard
    for (int mt = 0; mt < 4; ++mt) {
      bf16x8 wr[8];
#pragma unroll
      for (int ks = 0; ks < 8; ++ks)
        wr[ks] = Wfv[(size_t)((g * 4 + mt) * 8 + ks) * 64 + lane];
      f32x16 acc;
#pragma unroll
      for (int r = 0; r < 16; ++r) acc[r] = 0.f;
#pragma unroll
      for (int ks = 0; ks < 8; ++ks)
        acc = __builtin_amdgcn_mfma_f32_32x32x16_bf16(bfr[ks], wr[ks], acc, 0, 0, 0);
      const int ch = g * 128 + mt * 32 + l31;
#pragma unroll
      for (int r = 0; r < 16; ++r) {
        int row = (r & 3) + 8 * (r >> 2) + 4 * lh;
        Yt[row * 520 + ch] = f2bf(acc[r]);   // pad rows written, never read
      }
    }
  }
  __syncthreads();   // z-tile visible to all waves

#pragma unroll
  for (int bi = 0; bi < 2; ++bi) {
    float2* slab = (float2*)(out + (size_t)(b0 + bi) * 7680);
#pragma unroll 5
    for (int k = 0; k < 15; ++k) {
      int e0 = k * 512 + 2 * t;
      int ch0 = e0 / 15, p0 = e0 - ch0 * 15;
      int e1 = e0 + 1;
      int ch1 = e1 / 15, p1 = e1 - ch1 * 15;
      float f0 = bf2f(Yt[(bi * 16 + p0) * 520 + ch0]);
      float f1 = bf2f(Yt[(bi * 16 + p1) * 520 + ch1]);
      slab[k * 256 + t] = make_float2(
          fmaxf(fmaf(f0, aArr[ch0], bArr[ch0]), 0.f),
          fmaxf(fmaf(f1, aArr[ch1], bArr[ch1]), 0.f));
    }
  }
}

extern "C" void kernel_launch(void* const* d_in, const int* in_sizes, int n_in,
                              void* d_out, int out_size, void* d_ws, size_t ws_size,
                              hipStream_t stream) {
  const float* x = (const float*)d_in[0];
  const float* cw = (const float*)d_in[1];
  // d_in[2] = conv_b: cancelled exactly by training-mode BN -> unused
  const float* gamma = (const float*)d_in[3];
  const float* beta = (const float*)d_in[4];

  unsigned short* wf = (unsigned short*)d_ws;             // 8192*8 bf16 = 128 KB
  float2* Part = (float2*)(wf + 65536);                   // 1024*512 float2 = 4 MB
  float2* AB = Part + (size_t)1024 * 512;                 // 512 float2 = 4 KB

  hipLaunchKernelGGL(k_pass1, dim3(1024), dim3(256), 0, stream, x, cw, wf, Part);
  hipLaunchKernelGGL(k_stats, dim3(64), dim3(256), 0, stream, Part, gamma, beta, AB);
  hipLaunchKernelGGL(k_pass2, dim3(1024), dim3(256), 0, stream, x, wf, AB, (float*)d_out);
}